// Round 15
// baseline (19753.035 us; speedup 1.0000x reference)
//
#include <hip/hip_runtime.h>

// Encoder: 3-layer bidirectional-weights LSTM, H=256, B=64, T=1024, then
// 256->81 linear + argmax (softmax monotone -> dead).
//
// R21 = R18 (15562 us best) with the weight operand moved from LDS broadcast
// to the SCALAR memory path. Floor arithmetic (round-14): per CU per tick the
// K-phase issues ~3700 wave-uniform ds_read_b128; each moves 64x16B=1KB over
// the 128B/clock LDS return bus (broadcast still pays full width) -> ~29.7k
// cy ~ 12.4us = the observed K-phase. The kernel is LDS-return-BW-bound on
// weight reads (16B useful per 1KB of bus). Fix: weights are wave-uniform and
// read-only -> read from global with provably-uniform addresses (w is
// readfirstlane'd; k-offset readfirstlane'd for insurance) so the compiler
// selects s_load_dwordx4 (SMEM pipe; SGPR-sourced FMA is legal, 1 SGPR
// src/op). wlds + staging deleted (LDS ~50KB). FMA order/slices/epilogue
// byte-identical to R18 -> bit-identical output.
// Ledger: R9 more-blocks 2x LLC traffic; R10 pinned pipeline; R11/R16 ld16
// worse; R11 stride-16 red 2-bank; R17 acc spill (FETCH/WRITE explosion at
// flat VGPR = spill tripwire); R19 FETCH halved time worse (not LLC-BW-bound);
// R20 tied-float4 asm uncompilable (known since R6).

#define H_ 256
#define B_ 64
#define T_ 1024
#define NBLK 256
#define NTHR 1024
#define HBUF 98304     // floats per h ring buffer: 6 cells * 16384
#define NTICK 1026

// ws byte offsets
#define OFF_GEN  0
#define OFF_ROOT 64
#define OFF_CNT  128          // 8 counters, 64B apart
#define OFF_H    4096         // hbuf[2][6][16384] floats = 786432 B
#define OFF_XT   1048576      // xT2[1024][16][64][4] floats = 16 MB
#define OFF_YS   17825792     // ys[1024][64][256] floats = 64 MB

__device__ __forceinline__ float sigf(float x) {
  return 1.0f / (1.0f + __expf(-x));
}
__device__ __forceinline__ float tanhf_(float x) {
  float e = __expf(-2.0f * fabsf(x));
  float r = (1.0f - e) / (1.0f + e);
  return x >= 0.0f ? r : -r;
}

// ---- LLC-coherent (bypass L1/L2) access helpers (R8-proven) ----
__device__ __forceinline__ void llc_ld1(const float4* p, float4& r) {
  asm volatile(
      "global_load_dwordx4 %0, %1, off sc0 sc1\n\t"
      "s_waitcnt vmcnt(0)"
      : "=v"(r)
      : "v"(p)
      : "memory");
}
__device__ __forceinline__ void llc_ld4(const float4* p, float4& r0, float4& r1,
                                        float4& r2, float4& r3) {
  asm volatile(
      "global_load_dwordx4 %0, %4, off sc0 sc1\n\t"
      "global_load_dwordx4 %1, %4, off offset:1024 sc0 sc1\n\t"
      "global_load_dwordx4 %2, %4, off offset:2048 sc0 sc1\n\t"
      "global_load_dwordx4 %3, %4, off offset:3072 sc0 sc1\n\t"
      "s_waitcnt vmcnt(0)"
      : "=&v"(r0), "=&v"(r1), "=&v"(r2), "=&v"(r3)
      : "v"(p)
      : "memory");
}
// 8 consecutive k4 rows, one drain. Two address regs (13-bit signed offset cap).
__device__ __forceinline__ void llc_ld8(const float4* p, const float4* q,
                                        float4& r0, float4& r1, float4& r2,
                                        float4& r3, float4& r4, float4& r5,
                                        float4& r6, float4& r7) {
  asm volatile(
      "global_load_dwordx4 %0, %8, off sc0 sc1\n\t"
      "global_load_dwordx4 %1, %8, off offset:1024 sc0 sc1\n\t"
      "global_load_dwordx4 %2, %8, off offset:2048 sc0 sc1\n\t"
      "global_load_dwordx4 %3, %8, off offset:3072 sc0 sc1\n\t"
      "global_load_dwordx4 %4, %9, off sc0 sc1\n\t"
      "global_load_dwordx4 %5, %9, off offset:1024 sc0 sc1\n\t"
      "global_load_dwordx4 %6, %9, off offset:2048 sc0 sc1\n\t"
      "global_load_dwordx4 %7, %9, off offset:3072 sc0 sc1\n\t"
      "s_waitcnt vmcnt(0)"
      : "=&v"(r0), "=&v"(r1), "=&v"(r2), "=&v"(r3), "=&v"(r4), "=&v"(r5),
        "=&v"(r6), "=&v"(r7)
      : "v"(p), "v"(q)
      : "memory");
}
// paired h store (8B), NO drain -- one shared vmcnt(0) before the barrier
__device__ __forceinline__ void llc_st_f2(float* p, float2 v) {
  asm volatile("global_store_dwordx2 %0, %1, off sc0 sc1" ::"v"(p), "v"(v)
               : "memory");
}

// ---------------- x transpose: x[b][k][t] -> xT2[t][k>>2][b][k&3] ----------------
__global__ __launch_bounds__(64) void transpose_x(const float* __restrict__ x,
                                                  float* __restrict__ xT) {
  __shared__ float tile[64][65];
  const int k = blockIdx.y;
  const int t0 = blockIdx.x * 64;
  const int lane = threadIdx.x;
  for (int bi = 0; bi < 64; ++bi)
    tile[bi][lane] = x[bi * 65536 + k * 1024 + t0 + lane];
  __syncthreads();
  for (int ti = 0; ti < 64; ++ti)
    xT[(size_t)(t0 + ti) * 4096 + (k >> 2) * 256 + lane * 4 + (k & 3)] =
        tile[lane][ti];
}

// ---------------- 8-row FMA body, weights from GLOBAL via uniform addresses ----
// gb = matrix base + u0*S (uniform). Row offset ((a&3)*256 + (a>>2))*S is
// compile-time; kk*4 is wave-uniform (readfirstlane'd) -> SMEM s_load path.
// fmaf chain = exactly 4 v_fma_f32 per row (R15); FP order identical to R18.
template <int S>
__device__ __forceinline__ void body8u(float* __restrict__ acc, const float4 av,
                                       const float* __restrict__ gb,
                                       const int kk) {
  const int k4o = __builtin_amdgcn_readfirstlane(kk * 4);
#pragma unroll
  for (int a = 0; a < 8; ++a) {
    const float* wp = gb + ((a & 3) * 256 + (a >> 2)) * S + k4o;
    float4 wq = *(const float4*)wp;
    acc[a] = fmaf(wq.w, av.w,
                  fmaf(wq.z, av.z, fmaf(wq.y, av.y, fmaf(wq.x, av.x, acc[a]))));
  }
}

// LLC-path K runner: n k4-groups from bufbase at bufk4; weights from gb at
// local k-offset kloc (within ONE matrix; every call site is single-matrix).
template <int S>
__device__ __forceinline__ void runLLCU(float* __restrict__ acc,
                                        const float4* __restrict__ bufbase,
                                        const int bufk4, const int kloc,
                                        const int n,
                                        const float* __restrict__ gb,
                                        const int lane) {
  const float4* p = bufbase + (size_t)bufk4 * 64 + lane;
  int k = 0;
  for (; k + 8 <= n; k += 8) {
    float4 v0, v1, v2, v3, v4, v5, v6, v7;
    llc_ld8(p, p + 256, v0, v1, v2, v3, v4, v5, v6, v7);
    p += 512;
    body8u<S>(acc, v0, gb, kloc + k + 0);
    body8u<S>(acc, v1, gb, kloc + k + 1);
    body8u<S>(acc, v2, gb, kloc + k + 2);
    body8u<S>(acc, v3, gb, kloc + k + 3);
    body8u<S>(acc, v4, gb, kloc + k + 4);
    body8u<S>(acc, v5, gb, kloc + k + 5);
    body8u<S>(acc, v6, gb, kloc + k + 6);
    body8u<S>(acc, v7, gb, kloc + k + 7);
  }
  for (; k + 4 <= n; k += 4) {
    float4 v0, v1, v2, v3;
    llc_ld4(p, v0, v1, v2, v3);
    p += 256;
    body8u<S>(acc, v0, gb, kloc + k + 0);
    body8u<S>(acc, v1, gb, kloc + k + 1);
    body8u<S>(acc, v2, gb, kloc + k + 2);
    body8u<S>(acc, v3, gb, kloc + k + 3);
  }
  for (; k < n; ++k) {
    float4 v;
    llc_ld1(p, v);
    p += 64;
    body8u<S>(acc, v, gb, kloc + k);
  }
}

// cached-path x runner (xT: plain vector loads), weights from global uniform
template <int S>
__device__ __forceinline__ void runCachedU(float* __restrict__ acc,
                                           const float4* __restrict__ bufbase,
                                           const int n,
                                           const float* __restrict__ gb,
                                           const int lane) {
  const float4* p = bufbase + lane;
  int k = 0;
  for (; k + 4 <= n; k += 4) {
    float4 v0 = p[0], v1 = p[64], v2 = p[128], v3 = p[192];
    p += 256;
    body8u<S>(acc, v0, gb, k + 0);
    body8u<S>(acc, v1, gb, k + 1);
    body8u<S>(acc, v2, gb, k + 2);
    body8u<S>(acc, v3, gb, k + 3);
  }
  for (; k < n; ++k) {
    float4 v = *p;
    p += 64;
    body8u<S>(acc, v, gb, k);
  }
}

// ---------------- persistent skewed LSTM ----------------
__global__ __launch_bounds__(NTHR, 1) void lstm_persistent(
    const float* __restrict__ Wih0, const float* __restrict__ Whh0,
    const float* __restrict__ b0, const float* __restrict__ Wih12,
    const float* __restrict__ Whh12, const float* __restrict__ b12, char* wsb) {
  unsigned* gen = (unsigned*)(wsb + OFF_GEN);
  unsigned* root = (unsigned*)(wsb + OFF_ROOT);
  float* hb = (float*)(wsb + OFF_H);
  const float* xT = (const float*)(wsb + OFF_XT);
  float* ys = (float*)(wsb + OFF_YS);

  __shared__ float red[16][64][12];   // 48 KB, stride 12 (odd x4)
  __shared__ float cst[3][2][64];     // per-layer c state (1.5 KB)
  __shared__ float blds[3][8];        // biases: [cell][a] matching acc order

  const int bid = blockIdx.x;
  const int tid = threadIdx.x;
  const int lane = tid & 63;
  const int w = __builtin_amdgcn_readfirstlane(tid >> 6);  // uniform wave id
  const int d = bid >> 7;          // direction 0/1
  const int u0 = (bid & 127) * 2;  // unit tile base (even)

  // uniform weight bases (base + u0*stride); rows add ((a&3)*256+(a>>2))*S
  const float* gx0 = Wih0 + (size_t)d * 65536 + (size_t)u0 * 64;
  const float* gr0 = Whh0 + (size_t)d * 262144 + (size_t)u0 * 256;
  const float* gA1 = Wih12 + (size_t)d * 524288 + (size_t)u0 * 512;
  const float* gB1 = Whh12 + (size_t)d * 262144 + (size_t)u0 * 256;
  const float* gA2 = Wih12 + (size_t)(2 + d) * 524288 + (size_t)u0 * 512;
  const float* gB2 = Whh12 + (size_t)(2 + d) * 262144 + (size_t)u0 * 256;

  if (tid < 384) ((float*)cst)[tid] = 0.f;
  // biases: blds[cell][a] = bias_cell[(a&3)*256 + u0 + (a>>2)]
  if (tid < 24) {
    const int cell = tid >> 3, a = tid & 7;
    const float* bb = (cell == 0) ? (b0 + d * 1024)
                                  : ((cell == 1) ? (b12 + d * 1024)
                                                 : (b12 + (2 + d) * 1024));
    blds[cell][a] = bb[(a & 3) * 256 + u0 + (a >> 2)];
  }
  __syncthreads();

  unsigned* mycnt = (unsigned*)(wsb + OFF_CNT + (size_t)(bid & 7) * 64);

  for (unsigned tick = 0; tick < NTICK; ++tick) {
    const float* R = hb + ((tick + 1) & 1) * HBUF;  // produced last tick
    float* W = hb + (tick & 1) * HBUF;              // produced this tick
    const float4* Rf4 = (const float4*)R;

    const bool has0 = tick < 1024;
    const bool has1 = tick >= 1 && tick < 1025;
    const bool has2 = tick >= 2;

    float acc[8] = {0.f, 0.f, 0.f, 0.f, 0.f, 0.f, 0.f, 0.f};

    // ---- concurrent task phase: waves 0-3 L0, 4-9 L1, 10-15 L2 ----
    // (k4 slices identical to R18 -> identical per-gate FP order)
    if (w < 4) {
      if (has0) {
        // L0: K4=80 (16 x cached [Wih0, S=64] + 64 rec h LLC [Whh0, S=256])
        if (w == 0) {
          runCachedU<64>(acc, (const float4*)xT + (size_t)tick * 1024, 16, gx0,
                         lane);
          runLLCU<256>(acc, Rf4 + (size_t)d * 4096, 0, 0, 4, gr0, lane);
        } else {
          const int lo = 20 * w;  // task wk4; buffer/local k4 = lo-16
          runLLCU<256>(acc, Rf4 + (size_t)d * 4096, lo - 16, lo - 16, 20, gr0,
                       lane);
        }
      }
    } else if (w < 10) {
      if (has1) {
        // L1: wk4 0..128 = cells 0,1 [Wih12, S=512]; 128..192 = rec [S=256]
        const int wi = w - 4, lo = 32 * wi;
        if (wi < 4)
          runLLCU<512>(acc, Rf4, lo, lo, 32, gA1, lane);
        else
          runLLCU<256>(acc, Rf4 + (size_t)(2 + d) * 4096, lo - 128, lo - 128,
                       32, gB1, lane);
      }
    } else {
      if (has2) {
        // L2: wk4 0..128 = cells 2,3 [S=512]; 128..192 = rec [S=256]
        const int wi = w - 10, lo = 32 * wi;
        if (wi < 4)
          runLLCU<512>(acc, Rf4 + (size_t)2 * 4096, lo, lo, 32, gA2, lane);
        else
          runLLCU<256>(acc, Rf4 + (size_t)(4 + d) * 4096, lo - 128, lo - 128,
                       32, gB2, lane);
      }
    }

    // partials -> LDS (absent tasks write zeros; never read)
    *(float4*)&red[w][lane][0] = make_float4(acc[0], acc[1], acc[2], acc[3]);
    *(float4*)&red[w][lane][4] = make_float4(acc[4], acc[5], acc[6], acc[7]);
    __syncthreads();

    // ---- fused epilogue: 192 threads = 3 cells x 64 batch ----
    if (tid < 192) {
      const int cell = tid >> 6, b = tid & 63;
      const bool present = (cell == 0) ? has0 : ((cell == 1) ? has1 : has2);
      if (present) {
        const int w0 = (cell == 0) ? 0 : ((cell == 1) ? 4 : 10);
        const int nw = (cell == 0) ? 4 : 6;
        float g0 = blds[cell][0], g1 = blds[cell][1], g2 = blds[cell][2],
              g3 = blds[cell][3], g4 = blds[cell][4], g5 = blds[cell][5],
              g6 = blds[cell][6], g7 = blds[cell][7];
        for (int ww = w0; ww < w0 + nw; ++ww) {
          const float4* rp = (const float4*)&red[ww][b][0];
          float4 s0 = rp[0], s1 = rp[1];
          g0 += s0.x; g1 += s0.y; g2 += s0.z; g3 += s0.w;
          g4 += s1.x; g5 += s1.y; g6 += s1.z; g7 += s1.w;
        }
        const float iv0 = sigf(g0), fv0 = sigf(g1), gv0 = tanhf_(g2),
                    ov0 = sigf(g3);
        const float iv1 = sigf(g4), fv1 = sigf(g5), gv1 = tanhf_(g6),
                    ov1 = sigf(g7);
        float c0 = fv0 * cst[cell][0][b] + iv0 * gv0;
        float c1 = fv1 * cst[cell][1][b] + iv1 * gv1;
        cst[cell][0][b] = c0;
        cst[cell][1][b] = c1;
        const float h0 = ov0 * tanhf_(c0), h1 = ov1 * tanhf_(c1);
        const int cellidx = (cell == 0) ? d : ((cell == 1) ? (2 + d) : (4 + d));
        float* hp =
            W + (size_t)cellidx * 16384 + (u0 >> 2) * 256 + b * 4 + (u0 & 3);
        llc_st_f2(hp, make_float2(h0, h1));  // no drain; shared drain below
        if (cell == 2 && d == 1) {
          // plain cached store: consumed by conv_argmax after kernel end
          *(float2*)(ys + (size_t)((int)tick - 2) * 16384 + b * 256 + u0) =
              make_float2(h0, h1);
        }
      }
    }
    // single drain for all h/ys stores, then block barrier
    asm volatile("s_waitcnt vmcnt(0)" ::: "memory");
    __syncthreads();

    // -------- grid barrier: pure relaxed LLC atomics, NO fences --------
    if (tid == 0) {
      unsigned old = __hip_atomic_fetch_add(mycnt, 1u, __ATOMIC_RELAXED,
                                            __HIP_MEMORY_SCOPE_AGENT);
      if (old == (tick + 1) * (NBLK / 8) - 1) {
        unsigned r = __hip_atomic_fetch_add(root, 1u, __ATOMIC_RELAXED,
                                            __HIP_MEMORY_SCOPE_AGENT);
        if (r == (tick + 1) * 8 - 1) {
          __hip_atomic_store(gen, tick + 1, __ATOMIC_RELAXED,
                             __HIP_MEMORY_SCOPE_AGENT);
        }
      }
      while (__hip_atomic_load(gen, __ATOMIC_RELAXED, __HIP_MEMORY_SCOPE_AGENT) <
             tick + 1) {
        __builtin_amdgcn_s_sleep(2);
      }
    }
    __syncthreads();
  }
}

// ---------------- conv(256->81) + argmax ----------------
__global__ __launch_bounds__(256) void conv_argmax(const float* __restrict__ yst,
                                                   const float* __restrict__ cw,
                                                   const float* __restrict__ cb,
                                                   int* __restrict__ out) {
  const int t = blockIdx.x;
  const int tid = threadIdx.x, lane = tid & 63, w = tid >> 6;
  const float* yrow = yst + (size_t)t * (B_ * H_) + lane * H_;
  float best = -3.4e38f;
  int bi = 0;
  for (int og = 0; og < 3; ++og) {
    float acc[8];
    int ov[8];
#pragma unroll
    for (int m = 0; m < 8; ++m) {
      int o = w + 32 * og + 4 * m;
      ov[m] = (o < 81) ? o : 80;
      acc[m] = (o < 81) ? cb[o] : -3.4e38f;
    }
    for (int uu = 0; uu < H_; uu += 4) {
      float4 y4 = *(const float4*)(yrow + uu);
#pragma unroll
      for (int m = 0; m < 8; ++m) {
        const float* wr = cw + ov[m] * H_ + uu;
        acc[m] += wr[0] * y4.x + wr[1] * y4.y + wr[2] * y4.z + wr[3] * y4.w;
      }
    }
#pragma unroll
    for (int m = 0; m < 8; ++m) {
      int o = w + 32 * og + 4 * m;
      if (o < 81 && acc[m] > best) {
        best = acc[m];
        bi = o;
      }
    }
  }
  __shared__ float sv[4][64];
  __shared__ int si[4][64];
  sv[w][lane] = best;
  si[w][lane] = bi;
  __syncthreads();
  if (tid < 64) {
    float bv = sv[0][tid];
    int bo = si[0][tid];
#pragma unroll
    for (int ww = 1; ww < 4; ++ww) {
      float v = sv[ww][tid];
      int o = si[ww][tid];
      if (v > bv || (v == bv && o < bo)) {
        bv = v;
        bo = o;
      }
    }
    out[tid * T_ + t] = bo;
  }
}

extern "C" void kernel_launch(void* const* d_in, const int* in_sizes, int n_in,
                              void* d_out, int out_size, void* d_ws,
                              size_t ws_size, hipStream_t stream) {
  const float* x = (const float*)d_in[0];
  const float* Wih0 = (const float*)d_in[1];
  const float* Whh0 = (const float*)d_in[2];
  const float* b0 = (const float*)d_in[3];
  const float* Wih12 = (const float*)d_in[4];
  const float* Whh12 = (const float*)d_in[5];
  const float* b12 = (const float*)d_in[6];
  const float* cw = (const float*)d_in[7];
  const float* cb = (const float*)d_in[8];
  int* out = (int*)d_out;
  char* wsb = (char*)d_ws;

  // zero flags + h ring (ws is re-poisoned 0xAA before every launch)
  hipMemsetAsync(wsb, 0, OFF_H + 786432, stream);
  transpose_x<<<dim3(16, 64, 1), dim3(64, 1, 1), 0, stream>>>(
      x, (float*)(wsb + OFF_XT));
  lstm_persistent<<<dim3(NBLK, 1, 1), dim3(NTHR, 1, 1), 0, stream>>>(
      Wih0, Whh0, b0, Wih12, Whh12, b12, wsb);
  conv_argmax<<<dim3(T_, 1, 1), dim3(256, 1, 1), 0, stream>>>(
      (const float*)(wsb + OFF_YS), cw, cb, out);
}

// Round 16
// 15618.987 us; speedup vs baseline: 1.2647x; 1.2647x over previous
//
#include <hip/hip_runtime.h>

// Encoder: 3-layer bidirectional-weights LSTM, H=256, B=64, T=1024, then
// 256->81 linear + argmax (softmax monotone -> dead).
//
// R22: byte-exact revert to R18/R15 (15562 us, session best).
// R21 post-mortem (CLOSED): scalar-path weights (s_load) -> 19753 us.
// VGPR 64->36 and LDS 110->51 KB prove the conversion took effect; VALUBusy
// 58->22.5% proves the VALU idles on SMEM latency (~59 KB/CU/tick through
// the scalar pipe serializes worse than LDS broadcast). LDS-return-BW theory
// falsified: removing ALL weight ds_reads made it slower.
// Complete ledger of falsified levers around the R8 structure:
//  - R9  512x512 blocks: block count multiplies LLC broadcast traffic (x2).
//  - R10 split issue/wait + sched_barrier: order-pinning defeats scheduler.
//  - R11/R16 ld16: load-depth 8 optimal (16 regresses in healthy env).
//  - R11 red stride 16: 2-bank 32-way LDS conflict (stride 12 = odd x4).
//  - R17 straddler rebalance: acc scratch spill (FETCH/WRITE explosion at
//    flat VGPR = spill signature).
//  - R19 batch-split/unit-widen: FETCH halved, time worse (not LLC-BW-bound).
//  - R20 dataflow-tied pipeline: tied float4 asm operands uncompilable.
//  - R21 scalar-path weights: SMEM latency serializes (VALUBusy 22%).
// Wins kept: task-parallel waves 0-3/4-9/10-15 + fused 192-thr epilogue +
// llc_ld8 fused issue+drain (R8, 18.3->16.2 ms); fmaf-chain body8 (R15,
// 16.1->15.6-15.9 ms). The 15.5-15.9 ms band has absorbed nine structural
// experiments: latency-serialization equilibrium, no saturated pipe, no
// single named residual -> practical plateau for this structure.

#define H_ 256
#define B_ 64
#define T_ 1024
#define NBLK 256
#define NTHR 1024
#define HBUF 98304     // floats per h ring buffer: 6 cells * 16384
#define NTICK 1026

// ws byte offsets
#define OFF_GEN  0
#define OFF_ROOT 64
#define OFF_CNT  128          // 8 counters, 64B apart
#define OFF_H    4096         // hbuf[2][6][16384] floats = 786432 B
#define OFF_XT   1048576      // xT2[1024][16][64][4] floats = 16 MB
#define OFF_YS   17825792     // ys[1024][64][256] floats = 64 MB

__device__ __forceinline__ float sigf(float x) {
  return 1.0f / (1.0f + __expf(-x));
}
__device__ __forceinline__ float tanhf_(float x) {
  float e = __expf(-2.0f * fabsf(x));
  float r = (1.0f - e) / (1.0f + e);
  return x >= 0.0f ? r : -r;
}

// ---- LLC-coherent (bypass L1/L2) access helpers ----
__device__ __forceinline__ void llc_ld1(const float4* p, float4& r) {
  asm volatile(
      "global_load_dwordx4 %0, %1, off sc0 sc1\n\t"
      "s_waitcnt vmcnt(0)"
      : "=v"(r)
      : "v"(p)
      : "memory");
}
__device__ __forceinline__ void llc_ld4(const float4* p, float4& r0, float4& r1,
                                        float4& r2, float4& r3) {
  asm volatile(
      "global_load_dwordx4 %0, %4, off sc0 sc1\n\t"
      "global_load_dwordx4 %1, %4, off offset:1024 sc0 sc1\n\t"
      "global_load_dwordx4 %2, %4, off offset:2048 sc0 sc1\n\t"
      "global_load_dwordx4 %3, %4, off offset:3072 sc0 sc1\n\t"
      "s_waitcnt vmcnt(0)"
      : "=&v"(r0), "=&v"(r1), "=&v"(r2), "=&v"(r3)
      : "v"(p)
      : "memory");
}
// 8 consecutive k4 rows, one drain. Two address regs (13-bit signed offset cap).
__device__ __forceinline__ void llc_ld8(const float4* p, const float4* q,
                                        float4& r0, float4& r1, float4& r2,
                                        float4& r3, float4& r4, float4& r5,
                                        float4& r6, float4& r7) {
  asm volatile(
      "global_load_dwordx4 %0, %8, off sc0 sc1\n\t"
      "global_load_dwordx4 %1, %8, off offset:1024 sc0 sc1\n\t"
      "global_load_dwordx4 %2, %8, off offset:2048 sc0 sc1\n\t"
      "global_load_dwordx4 %3, %8, off offset:3072 sc0 sc1\n\t"
      "global_load_dwordx4 %4, %9, off sc0 sc1\n\t"
      "global_load_dwordx4 %5, %9, off offset:1024 sc0 sc1\n\t"
      "global_load_dwordx4 %6, %9, off offset:2048 sc0 sc1\n\t"
      "global_load_dwordx4 %7, %9, off offset:3072 sc0 sc1\n\t"
      "s_waitcnt vmcnt(0)"
      : "=&v"(r0), "=&v"(r1), "=&v"(r2), "=&v"(r3), "=&v"(r4), "=&v"(r5),
        "=&v"(r6), "=&v"(r7)
      : "v"(p), "v"(q)
      : "memory");
}
// paired h store (8B), NO drain -- one shared vmcnt(0) before the barrier
__device__ __forceinline__ void llc_st_f2(float* p, float2 v) {
  asm volatile("global_store_dwordx2 %0, %1, off sc0 sc1" ::"v"(p), "v"(v)
               : "memory");
}

// ---------------- x transpose: x[b][k][t] -> xT2[t][k>>2][b][k&3] ----------------
__global__ __launch_bounds__(64) void transpose_x(const float* __restrict__ x,
                                                  float* __restrict__ xT) {
  __shared__ float tile[64][65];
  const int k = blockIdx.y;
  const int t0 = blockIdx.x * 64;
  const int lane = threadIdx.x;
  for (int bi = 0; bi < 64; ++bi)
    tile[bi][lane] = x[bi * 65536 + k * 1024 + t0 + lane];
  __syncthreads();
  for (int ti = 0; ti < 64; ++ti)
    xT[(size_t)(t0 + ti) * 4096 + (k >> 2) * 256 + lane * 4 + (k & 3)] =
        tile[lane][ti];
}

// ---------------- 8-row FMA body for one k4 ----
// weights from LDS: wl[k4*32 + a*4 .. +3]  (wave-uniform ds_read_b128 broadcast)
// R15: explicit fmaf chain -> exactly 4 v_fma_f32 per row.
__device__ __forceinline__ void body8(float* __restrict__ acc, const float4 av,
                                      const float* __restrict__ wl,
                                      const int k4) {
  const float* wp = wl + (size_t)k4 * 32;
#pragma unroll
  for (int a = 0; a < 8; ++a) {
    float4 wq = *(const float4*)(wp + a * 4);
    acc[a] = fmaf(wq.w, av.w,
                  fmaf(wq.z, av.z, fmaf(wq.y, av.y, fmaf(wq.x, av.x, acc[a]))));
  }
}

// LLC-path K runner: n k4-groups from bufbase starting at buffer k4 `bufk4`,
// weight index starting at task-global `wk4`. Batches of 8 / 4 / 1.
__device__ __forceinline__ void runLLC(float* __restrict__ acc,
                                       const float4* __restrict__ bufbase,
                                       const int bufk4, const int wk4,
                                       const int n,
                                       const float* __restrict__ wl,
                                       const int lane) {
  const float4* p = bufbase + (size_t)bufk4 * 64 + lane;
  int k = 0;
  for (; k + 8 <= n; k += 8) {
    float4 v0, v1, v2, v3, v4, v5, v6, v7;
    llc_ld8(p, p + 256, v0, v1, v2, v3, v4, v5, v6, v7);
    p += 512;
    body8(acc, v0, wl, wk4 + k + 0);
    body8(acc, v1, wl, wk4 + k + 1);
    body8(acc, v2, wl, wk4 + k + 2);
    body8(acc, v3, wl, wk4 + k + 3);
    body8(acc, v4, wl, wk4 + k + 4);
    body8(acc, v5, wl, wk4 + k + 5);
    body8(acc, v6, wl, wk4 + k + 6);
    body8(acc, v7, wl, wk4 + k + 7);
  }
  for (; k + 4 <= n; k += 4) {
    float4 v0, v1, v2, v3;
    llc_ld4(p, v0, v1, v2, v3);
    p += 256;
    body8(acc, v0, wl, wk4 + k + 0);
    body8(acc, v1, wl, wk4 + k + 1);
    body8(acc, v2, wl, wk4 + k + 2);
    body8(acc, v3, wl, wk4 + k + 3);
  }
  for (; k < n; ++k) {
    float4 v;
    llc_ld1(p, v);
    p += 64;
    body8(acc, v, wl, wk4 + k);
  }
}

// cached-path K runner (xT: written by earlier kernel, plain loads ok)
__device__ __forceinline__ void runCached(float* __restrict__ acc,
                                          const float4* __restrict__ bufbase,
                                          const int bufk4, const int wk4,
                                          const int n,
                                          const float* __restrict__ wl,
                                          const int lane) {
  const float4* p = bufbase + (size_t)bufk4 * 64 + lane;
  int k = 0;
  for (; k + 4 <= n; k += 4) {
    float4 v0 = p[0], v1 = p[64], v2 = p[128], v3 = p[192];
    p += 256;
    body8(acc, v0, wl, wk4 + k + 0);
    body8(acc, v1, wl, wk4 + k + 1);
    body8(acc, v2, wl, wk4 + k + 2);
    body8(acc, v3, wl, wk4 + k + 3);
  }
  for (; k < n; ++k) {
    float4 v = *p;
    p += 64;
    body8(acc, v, wl, wk4 + k);
  }
}

// ---------------- persistent skewed LSTM ----------------
__global__ __launch_bounds__(NTHR, 1) void lstm_persistent(
    const float* __restrict__ Wih0, const float* __restrict__ Whh0,
    const float* __restrict__ b0, const float* __restrict__ Wih12,
    const float* __restrict__ Whh12, const float* __restrict__ b12, char* wsb) {
  unsigned* gen = (unsigned*)(wsb + OFF_GEN);
  unsigned* root = (unsigned*)(wsb + OFF_ROOT);
  float* hb = (float*)(wsb + OFF_H);
  const float* xT = (const float*)(wsb + OFF_XT);
  float* ys = (float*)(wsb + OFF_YS);

  __shared__ float red[16][64][12];   // 48 KB, stride 12 (odd x4)
  __shared__ float cst[3][2][64];     // per-layer c state (1.5 KB)
  __shared__ float wlds[14848];       // 59 KB: per-task [k4][8 rows][4]
  __shared__ float blds[3][8];        // biases: [cell][a] matching acc order

  const int bid = blockIdx.x;
  const int tid = threadIdx.x;
  const int lane = tid & 63;
  const int w = __builtin_amdgcn_readfirstlane(tid >> 6);  // uniform wave id
  const int d = bid >> 7;          // direction 0/1
  const int u0 = (bid & 127) * 2;  // unit tile base (even)

  if (tid < 384) ((float*)cst)[tid] = 0.f;

  // ---- stage all weights for this block into LDS (once) ----
  auto stage = [&](const float* wA, int wAs, const float* wB, int wBs,
                   int K4s, int NA4s, float* dst) {
    const int nq = K4s * 8;
    for (int idx = tid; idx < nq; idx += NTHR) {
      const int a = idx / K4s;
      const int k4 = idx - a * K4s;
      const int row = (a & 3) * 256 + u0 + (a >> 2);
      const float* src = (k4 < NA4s) ? (wA + (size_t)row * wAs + k4 * 4)
                                     : (wB + (size_t)row * wBs + (k4 - NA4s) * 4);
      float4 q = *(const float4*)src;
      *(float4*)(dst + ((size_t)k4 * 8 + a) * 4) = q;
    }
  };
  stage(Wih0 + (size_t)d * 65536, 64, Whh0 + (size_t)d * 262144, 256, 80, 16,
        wlds);
  stage(Wih12 + (size_t)d * 524288, 512, Whh12 + (size_t)d * 262144, 256, 192,
        128, wlds + 2560);
  stage(Wih12 + (size_t)(2 + d) * 524288, 512,
        Whh12 + (size_t)(2 + d) * 262144, 256, 192, 128, wlds + 8704);
  // biases: blds[cell][a] = bias_cell[(a&3)*256 + u0 + (a>>2)]
  if (tid < 24) {
    const int cell = tid >> 3, a = tid & 7;
    const float* bb = (cell == 0) ? (b0 + d * 1024)
                                  : ((cell == 1) ? (b12 + d * 1024)
                                                 : (b12 + (2 + d) * 1024));
    blds[cell][a] = bb[(a & 3) * 256 + u0 + (a >> 2)];
  }
  __syncthreads();

  unsigned* mycnt = (unsigned*)(wsb + OFF_CNT + (size_t)(bid & 7) * 64);

  for (unsigned tick = 0; tick < NTICK; ++tick) {
    const float* R = hb + ((tick + 1) & 1) * HBUF;  // produced last tick
    float* W = hb + (tick & 1) * HBUF;              // produced this tick
    const float4* Rf4 = (const float4*)R;

    const bool has0 = tick < 1024;
    const bool has1 = tick >= 1 && tick < 1025;
    const bool has2 = tick >= 2;

    float acc[8] = {0.f, 0.f, 0.f, 0.f, 0.f, 0.f, 0.f, 0.f};

    // ---- concurrent task phase: waves 0-3 L0, 4-9 L1, 10-15 L2 ----
    if (w < 4) {
      if (has0) {
        // L0: K4=80 (16 x cached + 64 rec h LLC), 20 k4 per wave
        if (w == 0) {
          runCached(acc, (const float4*)xT + (size_t)tick * 1024, 0, 0, 16,
                    wlds, lane);
          runLLC(acc, Rf4 + (size_t)d * 4096, 0, 16, 4, wlds, lane);
        } else {
          const int lo = 20 * w;  // task k4; h buffer k4 = lo-16
          runLLC(acc, Rf4 + (size_t)d * 4096, lo - 16, lo, 20, wlds, lane);
        }
      }
    } else if (w < 10) {
      if (has1) {
        // L1: K4=192 (128 = cells 0,1 ; 64 = rec cell 2+d), 32 k4 per wave
        const int wi = w - 4, lo = 32 * wi;
        if (wi < 4)
          runLLC(acc, Rf4, lo, lo, 32, wlds + 2560, lane);
        else
          runLLC(acc, Rf4 + (size_t)(2 + d) * 4096, lo - 128, lo, 32,
                 wlds + 2560, lane);
      }
    } else {
      if (has2) {
        // L2: K4=192 (128 = cells 2,3 ; 64 = rec cell 4+d), 32 k4 per wave
        const int wi = w - 10, lo = 32 * wi;
        if (wi < 4)
          runLLC(acc, Rf4 + (size_t)2 * 4096, lo, lo, 32, wlds + 8704, lane);
        else
          runLLC(acc, Rf4 + (size_t)(4 + d) * 4096, lo - 128, lo, 32,
                 wlds + 8704, lane);
      }
    }

    // partials -> LDS (absent tasks write zeros; never read)
    *(float4*)&red[w][lane][0] = make_float4(acc[0], acc[1], acc[2], acc[3]);
    *(float4*)&red[w][lane][4] = make_float4(acc[4], acc[5], acc[6], acc[7]);
    __syncthreads();

    // ---- fused epilogue: 192 threads = 3 cells x 64 batch ----
    if (tid < 192) {
      const int cell = tid >> 6, b = tid & 63;
      const bool present = (cell == 0) ? has0 : ((cell == 1) ? has1 : has2);
      if (present) {
        const int w0 = (cell == 0) ? 0 : ((cell == 1) ? 4 : 10);
        const int nw = (cell == 0) ? 4 : 6;
        float g0 = blds[cell][0], g1 = blds[cell][1], g2 = blds[cell][2],
              g3 = blds[cell][3], g4 = blds[cell][4], g5 = blds[cell][5],
              g6 = blds[cell][6], g7 = blds[cell][7];
        for (int ww = w0; ww < w0 + nw; ++ww) {
          const float4* rp = (const float4*)&red[ww][b][0];
          float4 s0 = rp[0], s1 = rp[1];
          g0 += s0.x; g1 += s0.y; g2 += s0.z; g3 += s0.w;
          g4 += s1.x; g5 += s1.y; g6 += s1.z; g7 += s1.w;
        }
        const float iv0 = sigf(g0), fv0 = sigf(g1), gv0 = tanhf_(g2),
                    ov0 = sigf(g3);
        const float iv1 = sigf(g4), fv1 = sigf(g5), gv1 = tanhf_(g6),
                    ov1 = sigf(g7);
        float c0 = fv0 * cst[cell][0][b] + iv0 * gv0;
        float c1 = fv1 * cst[cell][1][b] + iv1 * gv1;
        cst[cell][0][b] = c0;
        cst[cell][1][b] = c1;
        const float h0 = ov0 * tanhf_(c0), h1 = ov1 * tanhf_(c1);
        const int cellidx = (cell == 0) ? d : ((cell == 1) ? (2 + d) : (4 + d));
        float* hp =
            W + (size_t)cellidx * 16384 + (u0 >> 2) * 256 + b * 4 + (u0 & 3);
        llc_st_f2(hp, make_float2(h0, h1));  // no drain; shared drain below
        if (cell == 2 && d == 1) {
          // plain cached store: consumed by conv_argmax after kernel end
          *(float2*)(ys + (size_t)((int)tick - 2) * 16384 + b * 256 + u0) =
              make_float2(h0, h1);
        }
      }
    }
    // single drain for all h/ys stores, then block barrier
    asm volatile("s_waitcnt vmcnt(0)" ::: "memory");
    __syncthreads();

    // -------- grid barrier: pure relaxed LLC atomics, NO fences --------
    if (tid == 0) {
      unsigned old = __hip_atomic_fetch_add(mycnt, 1u, __ATOMIC_RELAXED,
                                            __HIP_MEMORY_SCOPE_AGENT);
      if (old == (tick + 1) * (NBLK / 8) - 1) {
        unsigned r = __hip_atomic_fetch_add(root, 1u, __ATOMIC_RELAXED,
                                            __HIP_MEMORY_SCOPE_AGENT);
        if (r == (tick + 1) * 8 - 1) {
          __hip_atomic_store(gen, tick + 1, __ATOMIC_RELAXED,
                             __HIP_MEMORY_SCOPE_AGENT);
        }
      }
      while (__hip_atomic_load(gen, __ATOMIC_RELAXED, __HIP_MEMORY_SCOPE_AGENT) <
             tick + 1) {
        __builtin_amdgcn_s_sleep(2);
      }
    }
    __syncthreads();
  }
}

// ---------------- conv(256->81) + argmax ----------------
__global__ __launch_bounds__(256) void conv_argmax(const float* __restrict__ yst,
                                                   const float* __restrict__ cw,
                                                   const float* __restrict__ cb,
                                                   int* __restrict__ out) {
  const int t = blockIdx.x;
  const int tid = threadIdx.x, lane = tid & 63, w = tid >> 6;
  const float* yrow = yst + (size_t)t * (B_ * H_) + lane * H_;
  float best = -3.4e38f;
  int bi = 0;
  for (int og = 0; og < 3; ++og) {
    float acc[8];
    int ov[8];
#pragma unroll
    for (int m = 0; m < 8; ++m) {
      int o = w + 32 * og + 4 * m;
      ov[m] = (o < 81) ? o : 80;
      acc[m] = (o < 81) ? cb[o] : -3.4e38f;
    }
    for (int uu = 0; uu < H_; uu += 4) {
      float4 y4 = *(const float4*)(yrow + uu);
#pragma unroll
      for (int m = 0; m < 8; ++m) {
        const float* wr = cw + ov[m] * H_ + uu;
        acc[m] += wr[0] * y4.x + wr[1] * y4.y + wr[2] * y4.z + wr[3] * y4.w;
      }
    }
#pragma unroll
    for (int m = 0; m < 8; ++m) {
      int o = w + 32 * og + 4 * m;
      if (o < 81 && acc[m] > best) {
        best = acc[m];
        bi = o;
      }
    }
  }
  __shared__ float sv[4][64];
  __shared__ int si[4][64];
  sv[w][lane] = best;
  si[w][lane] = bi;
  __syncthreads();
  if (tid < 64) {
    float bv = sv[0][tid];
    int bo = si[0][tid];
#pragma unroll
    for (int ww = 1; ww < 4; ++ww) {
      float v = sv[ww][tid];
      int o = si[ww][tid];
      if (v > bv || (v == bv && o < bo)) {
        bv = v;
        bo = o;
      }
    }
    out[tid * T_ + t] = bo;
  }
}

extern "C" void kernel_launch(void* const* d_in, const int* in_sizes, int n_in,
                              void* d_out, int out_size, void* d_ws,
                              size_t ws_size, hipStream_t stream) {
  const float* x = (const float*)d_in[0];
  const float* Wih0 = (const float*)d_in[1];
  const float* Whh0 = (const float*)d_in[2];
  const float* b0 = (const float*)d_in[3];
  const float* Wih12 = (const float*)d_in[4];
  const float* Whh12 = (const float*)d_in[5];
  const float* b12 = (const float*)d_in[6];
  const float* cw = (const float*)d_in[7];
  const float* cb = (const float*)d_in[8];
  int* out = (int*)d_out;
  char* wsb = (char*)d_ws;

  // zero flags + h ring (ws is re-poisoned 0xAA before every launch)
  hipMemsetAsync(wsb, 0, OFF_H + 786432, stream);
  transpose_x<<<dim3(16, 64, 1), dim3(64, 1, 1), 0, stream>>>(
      x, (float*)(wsb + OFF_XT));
  lstm_persistent<<<dim3(NBLK, 1, 1), dim3(NTHR, 1, 1), 0, stream>>>(
      Wih0, Whh0, b0, Wih12, Whh12, b12, wsb);
  conv_argmax<<<dim3(T_, 1, 1), dim3(256, 1, 1), 0, stream>>>(
      (const float*)(wsb + OFF_YS), cw, cb, out);
}

// Round 17
// 14812.601 us; speedup vs baseline: 1.3335x; 1.0544x over previous
//
#include <hip/hip_runtime.h>

// Encoder: 3-layer bidirectional-weights LSTM, H=256, B=64, T=1024, then
// 256->81 linear + argmax (softmax monotone -> dead).
//
// R23 = R22 (15619 us, session-best band 15.56-15.62 ms) with ONE change:
// grid-barrier release flattened. Old chain = 4 dependent LLC RTs (mycnt RMW
// -> root RMW -> gen store -> pollers observe gen). New: gen deleted; pollers
// poll root >= 8*(tick+1) directly (root is monotone, reaches exactly
// 8*(tick+1) when all 8 groups arrived; >= safe across ticks; max 8208).
// Arrival ordering unchanged: each block's RMW issues only after its
// vmcnt(0) h-store drain. Saves one LLC RT (~0.3us) per tick on the release
// path; risk is poll-flood/RMW queuing on the root line.
// Falsified-lever ledger (all counter-evidenced): R9 more-blocks = 2x LLC
// broadcast; R10 split-wait+sched_barrier pinning; R11/R16 load-depth 16;
// R11 stride-16 red (2-bank); R17 acc spill (FETCH/WRITE explosion at flat
// VGPR = spill signature); R19 traffic-halving null (not LLC-BW-bound);
// R20 tied-float4 asm uncompilable; R21 scalar-path weights (SMEM latency,
// VALUBusy 22%). Wins kept: R8 task-parallel waves + fused epilogue +
// llc_ld8; R15 fmaf-chain body8.

#define H_ 256
#define B_ 64
#define T_ 1024
#define NBLK 256
#define NTHR 1024
#define HBUF 98304     // floats per h ring buffer: 6 cells * 16384
#define NTICK 1026

// ws byte offsets
#define OFF_GEN  0            // (unused since R23; kept for layout stability)
#define OFF_ROOT 64
#define OFF_CNT  128          // 8 counters, 64B apart
#define OFF_H    4096         // hbuf[2][6][16384] floats = 786432 B
#define OFF_XT   1048576      // xT2[1024][16][64][4] floats = 16 MB
#define OFF_YS   17825792     // ys[1024][64][256] floats = 64 MB

__device__ __forceinline__ float sigf(float x) {
  return 1.0f / (1.0f + __expf(-x));
}
__device__ __forceinline__ float tanhf_(float x) {
  float e = __expf(-2.0f * fabsf(x));
  float r = (1.0f - e) / (1.0f + e);
  return x >= 0.0f ? r : -r;
}

// ---- LLC-coherent (bypass L1/L2) access helpers ----
__device__ __forceinline__ void llc_ld1(const float4* p, float4& r) {
  asm volatile(
      "global_load_dwordx4 %0, %1, off sc0 sc1\n\t"
      "s_waitcnt vmcnt(0)"
      : "=v"(r)
      : "v"(p)
      : "memory");
}
__device__ __forceinline__ void llc_ld4(const float4* p, float4& r0, float4& r1,
                                        float4& r2, float4& r3) {
  asm volatile(
      "global_load_dwordx4 %0, %4, off sc0 sc1\n\t"
      "global_load_dwordx4 %1, %4, off offset:1024 sc0 sc1\n\t"
      "global_load_dwordx4 %2, %4, off offset:2048 sc0 sc1\n\t"
      "global_load_dwordx4 %3, %4, off offset:3072 sc0 sc1\n\t"
      "s_waitcnt vmcnt(0)"
      : "=&v"(r0), "=&v"(r1), "=&v"(r2), "=&v"(r3)
      : "v"(p)
      : "memory");
}
// 8 consecutive k4 rows, one drain. Two address regs (13-bit signed offset cap).
__device__ __forceinline__ void llc_ld8(const float4* p, const float4* q,
                                        float4& r0, float4& r1, float4& r2,
                                        float4& r3, float4& r4, float4& r5,
                                        float4& r6, float4& r7) {
  asm volatile(
      "global_load_dwordx4 %0, %8, off sc0 sc1\n\t"
      "global_load_dwordx4 %1, %8, off offset:1024 sc0 sc1\n\t"
      "global_load_dwordx4 %2, %8, off offset:2048 sc0 sc1\n\t"
      "global_load_dwordx4 %3, %8, off offset:3072 sc0 sc1\n\t"
      "global_load_dwordx4 %4, %9, off sc0 sc1\n\t"
      "global_load_dwordx4 %5, %9, off offset:1024 sc0 sc1\n\t"
      "global_load_dwordx4 %6, %9, off offset:2048 sc0 sc1\n\t"
      "global_load_dwordx4 %7, %9, off offset:3072 sc0 sc1\n\t"
      "s_waitcnt vmcnt(0)"
      : "=&v"(r0), "=&v"(r1), "=&v"(r2), "=&v"(r3), "=&v"(r4), "=&v"(r5),
        "=&v"(r6), "=&v"(r7)
      : "v"(p), "v"(q)
      : "memory");
}
// paired h store (8B), NO drain -- one shared vmcnt(0) before the barrier
__device__ __forceinline__ void llc_st_f2(float* p, float2 v) {
  asm volatile("global_store_dwordx2 %0, %1, off sc0 sc1" ::"v"(p), "v"(v)
               : "memory");
}

// ---------------- x transpose: x[b][k][t] -> xT2[t][k>>2][b][k&3] ----------------
__global__ __launch_bounds__(64) void transpose_x(const float* __restrict__ x,
                                                  float* __restrict__ xT) {
  __shared__ float tile[64][65];
  const int k = blockIdx.y;
  const int t0 = blockIdx.x * 64;
  const int lane = threadIdx.x;
  for (int bi = 0; bi < 64; ++bi)
    tile[bi][lane] = x[bi * 65536 + k * 1024 + t0 + lane];
  __syncthreads();
  for (int ti = 0; ti < 64; ++ti)
    xT[(size_t)(t0 + ti) * 4096 + (k >> 2) * 256 + lane * 4 + (k & 3)] =
        tile[lane][ti];
}

// ---------------- 8-row FMA body for one k4 ----
// weights from LDS: wl[k4*32 + a*4 .. +3]  (wave-uniform ds_read_b128 broadcast)
// R15: explicit fmaf chain -> exactly 4 v_fma_f32 per row.
__device__ __forceinline__ void body8(float* __restrict__ acc, const float4 av,
                                      const float* __restrict__ wl,
                                      const int k4) {
  const float* wp = wl + (size_t)k4 * 32;
#pragma unroll
  for (int a = 0; a < 8; ++a) {
    float4 wq = *(const float4*)(wp + a * 4);
    acc[a] = fmaf(wq.w, av.w,
                  fmaf(wq.z, av.z, fmaf(wq.y, av.y, fmaf(wq.x, av.x, acc[a]))));
  }
}

// LLC-path K runner: n k4-groups from bufbase starting at buffer k4 `bufk4`,
// weight index starting at task-global `wk4`. Batches of 8 / 4 / 1.
__device__ __forceinline__ void runLLC(float* __restrict__ acc,
                                       const float4* __restrict__ bufbase,
                                       const int bufk4, const int wk4,
                                       const int n,
                                       const float* __restrict__ wl,
                                       const int lane) {
  const float4* p = bufbase + (size_t)bufk4 * 64 + lane;
  int k = 0;
  for (; k + 8 <= n; k += 8) {
    float4 v0, v1, v2, v3, v4, v5, v6, v7;
    llc_ld8(p, p + 256, v0, v1, v2, v3, v4, v5, v6, v7);
    p += 512;
    body8(acc, v0, wl, wk4 + k + 0);
    body8(acc, v1, wl, wk4 + k + 1);
    body8(acc, v2, wl, wk4 + k + 2);
    body8(acc, v3, wl, wk4 + k + 3);
    body8(acc, v4, wl, wk4 + k + 4);
    body8(acc, v5, wl, wk4 + k + 5);
    body8(acc, v6, wl, wk4 + k + 6);
    body8(acc, v7, wl, wk4 + k + 7);
  }
  for (; k + 4 <= n; k += 4) {
    float4 v0, v1, v2, v3;
    llc_ld4(p, v0, v1, v2, v3);
    p += 256;
    body8(acc, v0, wl, wk4 + k + 0);
    body8(acc, v1, wl, wk4 + k + 1);
    body8(acc, v2, wl, wk4 + k + 2);
    body8(acc, v3, wl, wk4 + k + 3);
  }
  for (; k < n; ++k) {
    float4 v;
    llc_ld1(p, v);
    p += 64;
    body8(acc, v, wl, wk4 + k);
  }
}

// cached-path K runner (xT: written by earlier kernel, plain loads ok)
__device__ __forceinline__ void runCached(float* __restrict__ acc,
                                          const float4* __restrict__ bufbase,
                                          const int bufk4, const int wk4,
                                          const int n,
                                          const float* __restrict__ wl,
                                          const int lane) {
  const float4* p = bufbase + (size_t)bufk4 * 64 + lane;
  int k = 0;
  for (; k + 4 <= n; k += 4) {
    float4 v0 = p[0], v1 = p[64], v2 = p[128], v3 = p[192];
    p += 256;
    body8(acc, v0, wl, wk4 + k + 0);
    body8(acc, v1, wl, wk4 + k + 1);
    body8(acc, v2, wl, wk4 + k + 2);
    body8(acc, v3, wl, wk4 + k + 3);
  }
  for (; k < n; ++k) {
    float4 v = *p;
    p += 64;
    body8(acc, v, wl, wk4 + k);
  }
}

// ---------------- persistent skewed LSTM ----------------
__global__ __launch_bounds__(NTHR, 1) void lstm_persistent(
    const float* __restrict__ Wih0, const float* __restrict__ Whh0,
    const float* __restrict__ b0, const float* __restrict__ Wih12,
    const float* __restrict__ Whh12, const float* __restrict__ b12, char* wsb) {
  unsigned* root = (unsigned*)(wsb + OFF_ROOT);
  float* hb = (float*)(wsb + OFF_H);
  const float* xT = (const float*)(wsb + OFF_XT);
  float* ys = (float*)(wsb + OFF_YS);

  __shared__ float red[16][64][12];   // 48 KB, stride 12 (odd x4)
  __shared__ float cst[3][2][64];     // per-layer c state (1.5 KB)
  __shared__ float wlds[14848];       // 59 KB: per-task [k4][8 rows][4]
  __shared__ float blds[3][8];        // biases: [cell][a] matching acc order

  const int bid = blockIdx.x;
  const int tid = threadIdx.x;
  const int lane = tid & 63;
  const int w = __builtin_amdgcn_readfirstlane(tid >> 6);  // uniform wave id
  const int d = bid >> 7;          // direction 0/1
  const int u0 = (bid & 127) * 2;  // unit tile base (even)

  if (tid < 384) ((float*)cst)[tid] = 0.f;

  // ---- stage all weights for this block into LDS (once) ----
  auto stage = [&](const float* wA, int wAs, const float* wB, int wBs,
                   int K4s, int NA4s, float* dst) {
    const int nq = K4s * 8;
    for (int idx = tid; idx < nq; idx += NTHR) {
      const int a = idx / K4s;
      const int k4 = idx - a * K4s;
      const int row = (a & 3) * 256 + u0 + (a >> 2);
      const float* src = (k4 < NA4s) ? (wA + (size_t)row * wAs + k4 * 4)
                                     : (wB + (size_t)row * wBs + (k4 - NA4s) * 4);
      float4 q = *(const float4*)src;
      *(float4*)(dst + ((size_t)k4 * 8 + a) * 4) = q;
    }
  };
  stage(Wih0 + (size_t)d * 65536, 64, Whh0 + (size_t)d * 262144, 256, 80, 16,
        wlds);
  stage(Wih12 + (size_t)d * 524288, 512, Whh12 + (size_t)d * 262144, 256, 192,
        128, wlds + 2560);
  stage(Wih12 + (size_t)(2 + d) * 524288, 512,
        Whh12 + (size_t)(2 + d) * 262144, 256, 192, 128, wlds + 8704);
  // biases: blds[cell][a] = bias_cell[(a&3)*256 + u0 + (a>>2)]
  if (tid < 24) {
    const int cell = tid >> 3, a = tid & 7;
    const float* bb = (cell == 0) ? (b0 + d * 1024)
                                  : ((cell == 1) ? (b12 + d * 1024)
                                                 : (b12 + (2 + d) * 1024));
    blds[cell][a] = bb[(a & 3) * 256 + u0 + (a >> 2)];
  }
  __syncthreads();

  unsigned* mycnt = (unsigned*)(wsb + OFF_CNT + (size_t)(bid & 7) * 64);

  for (unsigned tick = 0; tick < NTICK; ++tick) {
    const float* R = hb + ((tick + 1) & 1) * HBUF;  // produced last tick
    float* W = hb + (tick & 1) * HBUF;              // produced this tick
    const float4* Rf4 = (const float4*)R;

    const bool has0 = tick < 1024;
    const bool has1 = tick >= 1 && tick < 1025;
    const bool has2 = tick >= 2;

    float acc[8] = {0.f, 0.f, 0.f, 0.f, 0.f, 0.f, 0.f, 0.f};

    // ---- concurrent task phase: waves 0-3 L0, 4-9 L1, 10-15 L2 ----
    if (w < 4) {
      if (has0) {
        // L0: K4=80 (16 x cached + 64 rec h LLC), 20 k4 per wave
        if (w == 0) {
          runCached(acc, (const float4*)xT + (size_t)tick * 1024, 0, 0, 16,
                    wlds, lane);
          runLLC(acc, Rf4 + (size_t)d * 4096, 0, 16, 4, wlds, lane);
        } else {
          const int lo = 20 * w;  // task k4; h buffer k4 = lo-16
          runLLC(acc, Rf4 + (size_t)d * 4096, lo - 16, lo, 20, wlds, lane);
        }
      }
    } else if (w < 10) {
      if (has1) {
        // L1: K4=192 (128 = cells 0,1 ; 64 = rec cell 2+d), 32 k4 per wave
        const int wi = w - 4, lo = 32 * wi;
        if (wi < 4)
          runLLC(acc, Rf4, lo, lo, 32, wlds + 2560, lane);
        else
          runLLC(acc, Rf4 + (size_t)(2 + d) * 4096, lo - 128, lo, 32,
                 wlds + 2560, lane);
      }
    } else {
      if (has2) {
        // L2: K4=192 (128 = cells 2,3 ; 64 = rec cell 4+d), 32 k4 per wave
        const int wi = w - 10, lo = 32 * wi;
        if (wi < 4)
          runLLC(acc, Rf4 + (size_t)2 * 4096, lo, lo, 32, wlds + 8704, lane);
        else
          runLLC(acc, Rf4 + (size_t)(4 + d) * 4096, lo - 128, lo, 32,
                 wlds + 8704, lane);
      }
    }

    // partials -> LDS (absent tasks write zeros; never read)
    *(float4*)&red[w][lane][0] = make_float4(acc[0], acc[1], acc[2], acc[3]);
    *(float4*)&red[w][lane][4] = make_float4(acc[4], acc[5], acc[6], acc[7]);
    __syncthreads();

    // ---- fused epilogue: 192 threads = 3 cells x 64 batch ----
    if (tid < 192) {
      const int cell = tid >> 6, b = tid & 63;
      const bool present = (cell == 0) ? has0 : ((cell == 1) ? has1 : has2);
      if (present) {
        const int w0 = (cell == 0) ? 0 : ((cell == 1) ? 4 : 10);
        const int nw = (cell == 0) ? 4 : 6;
        float g0 = blds[cell][0], g1 = blds[cell][1], g2 = blds[cell][2],
              g3 = blds[cell][3], g4 = blds[cell][4], g5 = blds[cell][5],
              g6 = blds[cell][6], g7 = blds[cell][7];
        for (int ww = w0; ww < w0 + nw; ++ww) {
          const float4* rp = (const float4*)&red[ww][b][0];
          float4 s0 = rp[0], s1 = rp[1];
          g0 += s0.x; g1 += s0.y; g2 += s0.z; g3 += s0.w;
          g4 += s1.x; g5 += s1.y; g6 += s1.z; g7 += s1.w;
        }
        const float iv0 = sigf(g0), fv0 = sigf(g1), gv0 = tanhf_(g2),
                    ov0 = sigf(g3);
        const float iv1 = sigf(g4), fv1 = sigf(g5), gv1 = tanhf_(g6),
                    ov1 = sigf(g7);
        float c0 = fv0 * cst[cell][0][b] + iv0 * gv0;
        float c1 = fv1 * cst[cell][1][b] + iv1 * gv1;
        cst[cell][0][b] = c0;
        cst[cell][1][b] = c1;
        const float h0 = ov0 * tanhf_(c0), h1 = ov1 * tanhf_(c1);
        const int cellidx = (cell == 0) ? d : ((cell == 1) ? (2 + d) : (4 + d));
        float* hp =
            W + (size_t)cellidx * 16384 + (u0 >> 2) * 256 + b * 4 + (u0 & 3);
        llc_st_f2(hp, make_float2(h0, h1));  // no drain; shared drain below
        if (cell == 2 && d == 1) {
          // plain cached store: consumed by conv_argmax after kernel end
          *(float2*)(ys + (size_t)((int)tick - 2) * 16384 + b * 256 + u0) =
              make_float2(h0, h1);
        }
      }
    }
    // single drain for all h/ys stores, then block barrier
    asm volatile("s_waitcnt vmcnt(0)" ::: "memory");
    __syncthreads();

    // -------- grid barrier: relaxed LLC atomics, flattened release --------
    // arrive: group counter; group-last bumps root. release: poll root
    // directly (monotone; == 8*(tick+1) when all groups arrived).
    if (tid == 0) {
      unsigned old = __hip_atomic_fetch_add(mycnt, 1u, __ATOMIC_RELAXED,
                                            __HIP_MEMORY_SCOPE_AGENT);
      if (old == (tick + 1) * (NBLK / 8) - 1) {
        __hip_atomic_fetch_add(root, 1u, __ATOMIC_RELAXED,
                               __HIP_MEMORY_SCOPE_AGENT);
      }
      while (__hip_atomic_load(root, __ATOMIC_RELAXED,
                               __HIP_MEMORY_SCOPE_AGENT) < (tick + 1) * 8) {
        __builtin_amdgcn_s_sleep(2);
      }
    }
    __syncthreads();
  }
}

// ---------------- conv(256->81) + argmax ----------------
__global__ __launch_bounds__(256) void conv_argmax(const float* __restrict__ yst,
                                                   const float* __restrict__ cw,
                                                   const float* __restrict__ cb,
                                                   int* __restrict__ out) {
  const int t = blockIdx.x;
  const int tid = threadIdx.x, lane = tid & 63, w = tid >> 6;
  const float* yrow = yst + (size_t)t * (B_ * H_) + lane * H_;
  float best = -3.4e38f;
  int bi = 0;
  for (int og = 0; og < 3; ++og) {
    float acc[8];
    int ov[8];
#pragma unroll
    for (int m = 0; m < 8; ++m) {
      int o = w + 32 * og + 4 * m;
      ov[m] = (o < 81) ? o : 80;
      acc[m] = (o < 81) ? cb[o] : -3.4e38f;
    }
    for (int uu = 0; uu < H_; uu += 4) {
      float4 y4 = *(const float4*)(yrow + uu);
#pragma unroll
      for (int m = 0; m < 8; ++m) {
        const float* wr = cw + ov[m] * H_ + uu;
        acc[m] += wr[0] * y4.x + wr[1] * y4.y + wr[2] * y4.z + wr[3] * y4.w;
      }
    }
#pragma unroll
    for (int m = 0; m < 8; ++m) {
      int o = w + 32 * og + 4 * m;
      if (o < 81 && acc[m] > best) {
        best = acc[m];
        bi = o;
      }
    }
  }
  __shared__ float sv[4][64];
  __shared__ int si[4][64];
  sv[w][lane] = best;
  si[w][lane] = bi;
  __syncthreads();
  if (tid < 64) {
    float bv = sv[0][tid];
    int bo = si[0][tid];
#pragma unroll
    for (int ww = 1; ww < 4; ++ww) {
      float v = sv[ww][tid];
      int o = si[ww][tid];
      if (v > bv || (v == bv && o < bo)) {
        bv = v;
        bo = o;
      }
    }
    out[tid * T_ + t] = bo;
  }
}

extern "C" void kernel_launch(void* const* d_in, const int* in_sizes, int n_in,
                              void* d_out, int out_size, void* d_ws,
                              size_t ws_size, hipStream_t stream) {
  const float* x = (const float*)d_in[0];
  const float* Wih0 = (const float*)d_in[1];
  const float* Whh0 = (const float*)d_in[2];
  const float* b0 = (const float*)d_in[3];
  const float* Wih12 = (const float*)d_in[4];
  const float* Whh12 = (const float*)d_in[5];
  const float* b12 = (const float*)d_in[6];
  const float* cw = (const float*)d_in[7];
  const float* cb = (const float*)d_in[8];
  int* out = (int*)d_out;
  char* wsb = (char*)d_ws;

  // zero flags + h ring (ws is re-poisoned 0xAA before every launch)
  hipMemsetAsync(wsb, 0, OFF_H + 786432, stream);
  transpose_x<<<dim3(16, 64, 1), dim3(64, 1, 1), 0, stream>>>(
      x, (float*)(wsb + OFF_XT));
  lstm_persistent<<<dim3(NBLK, 1, 1), dim3(NTHR, 1, 1), 0, stream>>>(
      Wih0, Whh0, b0, Wih12, Whh12, b12, wsb);
  conv_argmax<<<dim3(T_, 1, 1), dim3(256, 1, 1), 0, stream>>>(
      (const float*)(wsb + OFF_YS), cw, cb, out);
}